// Round 8
// baseline (121.411 us; speedup 1.0000x reference)
//
#include <hip/hip_runtime.h>

// CTC forward NLL (warp-ctc semantics), B=32 T=1024 V=1024 L=128, S=2L+1=257.
// Phase 1: per-(b,t) row softmax -> LINEAR probs: blank to pB[B*T], target
//          labels to packed rows pQ[(b*T+t)*128+j], cols j>=tgtlen[b] zeroed.
// Phase 2: wave = batch element, 8 waves per 512-thread block (4 blocks) so
//          2 waves/SIMD hide each other's stalls. 4 s-slots per lane (+1 on
//          lane 63). LINEAR-domain recursion; wave-uniform pow-2 rescale every
//          8 steps (DPP max-reduce, target 2^120). 16-timestep LDS double
//          buffer per wave via global_load_lds; 8-step register groups;
//          DPP wave_shr:1 for the cross-lane alpha[4l-1] term.

#define LOG2E 1.4426950408889634f
#define LN2   0.6931471805599453f

constexpr int B = 32, T = 1024, V = 1024, L = 128;
constexpr int S = 2 * L + 1;   // 257
constexpr int TS = 16;         // timesteps staged per LDS block (per wave)
constexpr int WPB = 8;         // waves (= batches) per workgroup

// native hw transcendentals: v_exp_f32 = 2^x, v_log_f32 = log2(x)
__device__ inline float fexp2(float x) { return __builtin_amdgcn_exp2f(x); }
__device__ inline float flog2(float x) { return __builtin_amdgcn_logf(x); }

template<int CTRL>
__device__ inline float dpp_mov(float old_, float x) {
    return __int_as_float(__builtin_amdgcn_update_dpp(
        __float_as_int(old_), __float_as_int(x), CTRL, 0xF, 0xF, false));
}

// ---- Kernel 1: softmax denominator + linear-prob gather ---------------------
__global__ __launch_bounds__(256) void k_lse_gather(
    const float* __restrict__ logits, const int* __restrict__ targets,
    const int* __restrict__ tgtlen,
    float* __restrict__ pQ, float* __restrict__ pB)
{
    const int row = blockIdx.x;          // b*T + t
    const int b   = row >> 10;           // T = 1024
    const float* x = logits + (size_t)row * V;
    const int tid = threadIdx.x;

    float4 v = reinterpret_cast<const float4*>(x)[tid];   // coalesced 4 KB row
    float m = fmaxf(fmaxf(v.x, v.y), fmaxf(v.z, v.w));
    #pragma unroll
    for (int off = 32; off; off >>= 1) m = fmaxf(m, __shfl_xor(m, off));

    __shared__ float red[8];
    const int lane = tid & 63, wv = tid >> 6;
    if (lane == 0) red[wv] = m;
    __syncthreads();
    m = fmaxf(fmaxf(red[0], red[1]), fmaxf(red[2], red[3]));

    float s = fexp2((v.x - m) * LOG2E) + fexp2((v.y - m) * LOG2E)
            + fexp2((v.z - m) * LOG2E) + fexp2((v.w - m) * LOG2E);
    #pragma unroll
    for (int off = 32; off; off >>= 1) s += __shfl_xor(s, off);
    if (lane == 0) red[4 + wv] = s;
    __syncthreads();
    s = red[4] + red[5] + red[6] + red[7];

    const float lse2 = m * LOG2E + flog2(s);   // log2 of softmax denom (shifted)
    if (tid == 0) {
        pB[row] = fexp2(x[0] * LOG2E - lse2);               // blank prob
    } else if (tid <= L) {
        const int j  = tid - 1;
        const int tl = tgtlen[b];
        const int lab = targets[b * L + j];
        // zero cols j >= tl: invalid lattice slots stay exactly 0 in phase 2.
        pQ[(size_t)row * 128 + j] =
            (j < tl) ? fexp2(x[lab] * LOG2E - lse2) : 0.0f;
    }
}

// ---- Kernel 2: linear-domain alpha recursion --------------------------------
__global__ __launch_bounds__(512) void k_ctc_alpha(
    const float* __restrict__ pQ, const float* __restrict__ pB,
    const int* __restrict__ targets, const int* __restrict__ loglen,
    const int* __restrict__ tgtlen, float* __restrict__ out)
{
    __shared__ __align__(16) float sQ[WPB * 2 * TS * 128];   // 128 KB
    __shared__ __align__(16) float sB[WPB * 2 * 64];         // 4 KB
    __shared__ float al[WPB * (S + 3)];                      // ~8.3 KB

    const int l   = threadIdx.x & 63;                        // lane
    const int wid = __builtin_amdgcn_readfirstlane((int)(threadIdx.x >> 6));
    const int b   = blockIdx.x * WPB + wid;                  // batch element
    const int len = loglen[b];           // in [512, 1024]
    const int tl  = tgtlen[b];           // in [64, 128]

    const int* tg = targets + b * L;
    const int t2l   = tg[2 * l];
    const int t2lm1 = (l > 0) ? tg[2 * l - 1] : -3;
    const int t2lp1 = tg[2 * l + 1];
    const float cs1f = (t2l != t2lm1) ? 1.0f : 0.0f;   // skip into s=4l+1
    const float cs3f = (t2lp1 != t2l) ? 1.0f : 0.0f;   // skip into s=4l+3

    // t = 0 init (true scale, Se = 0)
    float A0 = (l == 0) ? pB[(size_t)b * T] : 0.0f;
    float A1 = (l == 0) ? pQ[(size_t)b * T * 128] : 0.0f;
    float A2 = 0.0f, A3 = 0.0f, A4 = 0.0f;
    float p3 = 0.0f;                     // alpha[4l-1] carried from prev step
    int Se = 0;                          // accumulated log2 of removed scale

    // per-wave LDS slices (wave-uniform bases)
    float* sQw = sQ + wid * (2 * TS * 128);
    float* sBw = sB + wid * (2 * 64);
    float* alw = al + wid * (S + 3);

    // per-lane global bases
    const float* gQ = pQ + (size_t)b * T * 128 + (l & 31) * 4;
    const float* gB = pB + (size_t)b * T;

    #define STAGE(buf, t0)                                                     \
    {                                                                          \
        _Pragma("unroll")                                                      \
        for (int c = 0; c < TS / 2; ++c) {                                     \
            const int r  = (t0) + 2 * c + (l >> 5);                            \
            const int rc = (r < T) ? r : (T - 1);                              \
            const float* gp = gQ + (size_t)rc * 128;                           \
            __builtin_amdgcn_global_load_lds(                                  \
                (const __attribute__((address_space(1))) void*)gp,             \
                (__attribute__((address_space(3))) void*)                      \
                    (sQw + (buf) * (TS * 128) + 2 * c * 128),                  \
                16, 0, 0);                                                     \
        }                                                                      \
        {                                                                      \
            const int r  = (t0) + l;                                           \
            const int rc = (r < T) ? r : (T - 1);                              \
            const float* gp = gB + rc;                                         \
            __builtin_amdgcn_global_load_lds(                                  \
                (const __attribute__((address_space(1))) void*)gp,             \
                (__attribute__((address_space(3))) void*)                      \
                    (sBw + (buf) * 64),                                        \
                4, 0, 0);                                                      \
        }                                                                      \
    }

    // 8-step register groups (all indices compile-time)
    float2 qa[8]; float ba[8];
    float2 qb[8]; float bbf[8];

    #define LOADG(QD, BD, buf, r0)                                             \
    {                                                                          \
        _Pragma("unroll")                                                      \
        for (int r = 0; r < 8; ++r) {                                          \
            QD[r] = *reinterpret_cast<const float2*>(                          \
                sQw + (buf) * (TS * 128) + ((r0) + r) * 128 + 2 * l);          \
            BD[r] = sBw[(buf) * 64 + (r0) + r];                                \
        }                                                                      \
    }

    #define STEP_ONE(pb, p1, pl3)                                              \
    {                                                                          \
        const float n0 = (A0 + p3) * (pb);                                     \
        const float n1 = fmaf(cs1f, p3, A1 + A0) * (p1);                       \
        const float n2 = (A2 + A1) * (pb);                                     \
        const float n3 = fmaf(cs3f, A1, A3 + A2) * (pl3);                      \
        const float n4 = (A4 + A3) * (pb);                                     \
        A0 = n0; A1 = n1; A2 = n2; A3 = n3; A4 = n4;                           \
        p3 = dpp_mov<0x138>(0.0f, A3);     /* wave_shr:1, lane0 <- 0 */        \
    }

    // wave-uniform power-of-2 rescale: normalize max toward 2^120
    #define RESCALE()                                                          \
    {                                                                          \
        float m_ = fmaxf(fmaxf(A0, A1), fmaxf(A2, fmaxf(A3, A4)));             \
        m_ = fmaxf(m_, dpp_mov<0x111>(m_, m_));   /* row_shr:1  */             \
        m_ = fmaxf(m_, dpp_mov<0x112>(m_, m_));   /* row_shr:2  */             \
        m_ = fmaxf(m_, dpp_mov<0x114>(m_, m_));   /* row_shr:4  */             \
        m_ = fmaxf(m_, dpp_mov<0x118>(m_, m_));   /* row_shr:8  */             \
        m_ = fmaxf(m_, dpp_mov<0x142>(m_, m_));   /* row_bcast:15 */           \
        m_ = fmaxf(m_, dpp_mov<0x143>(m_, m_));   /* row_bcast:31 */           \
        const int e = (__builtin_amdgcn_readlane(__float_as_int(m_), 63)       \
                       >> 23) & 0xff;                                          \
        int kb = 374 - e;                  /* scale = 2^(247-e), biased */     \
        if (kb > 254) kb = 254;            /* clamp, self-recovers */          \
        const float sc = __int_as_float(kb << 23);                             \
        A0 *= sc; A1 *= sc; A2 *= sc; A3 *= sc; A4 *= sc; p3 *= sc;            \
        Se -= (kb - 127);                                                      \
    }

    STAGE(0, 1);                         // prologue: rows 1..TS -> buf 0
    int cb = 0;

    int tb = 1;
    for (; tb + TS <= len; tb += TS) {   // full blocks, no per-step guards
        asm volatile("s_waitcnt vmcnt(0)" ::: "memory");
        STAGE(cb ^ 1, tb + TS);
        LOADG(qa, ba, cb, 0);
        LOADG(qb, bbf, cb, 8);
        #pragma unroll
        for (int i = 0; i < 8; ++i) { STEP_ONE(ba[i],  qa[i].x, qa[i].y); }
        RESCALE();
        #pragma unroll
        for (int i = 0; i < 8; ++i) { STEP_ONE(bbf[i], qb[i].x, qb[i].y); }
        RESCALE();
        cb ^= 1;
    }
    if (tb < len) {                      // guarded tail (< TS steps)
        asm volatile("s_waitcnt vmcnt(0)" ::: "memory");
        LOADG(qa, ba, cb, 0);
        LOADG(qb, bbf, cb, 8);
        #pragma unroll
        for (int i = 0; i < 8; ++i) {
            if (tb + i < len) { STEP_ONE(ba[i], qa[i].x, qa[i].y); }
        }
        if (tb + 7 < len) RESCALE();
        #pragma unroll
        for (int i = 0; i < 8; ++i) {
            if (tb + 8 + i < len) { STEP_ONE(bbf[i], qb[i].x, qb[i].y); }
        }
    }
    #undef STEP_ONE
    #undef RESCALE
    #undef LOADG
    #undef STAGE

    alw[4 * l + 0] = A0;
    alw[4 * l + 1] = A1;
    alw[4 * l + 2] = A2;
    alw[4 * l + 3] = A3;
    if (l == 63) alw[256] = A4;
    __syncthreads();

    if (l == 0) {
        const float sum = alw[2 * tl] + alw[2 * tl - 1];
        out[b] = -LN2 * (flog2(sum) + (float)Se);
    }
}

extern "C" void kernel_launch(void* const* d_in, const int* in_sizes, int n_in,
                              void* d_out, int out_size, void* d_ws, size_t ws_size,
                              hipStream_t stream) {
    const float* logits  = (const float*)d_in[0];
    const int*   targets = (const int*)d_in[1];
    const int*   loglen  = (const int*)d_in[2];
    const int*   tgtlen  = (const int*)d_in[3];
    float* out = (float*)d_out;
    float* pQ = (float*)d_ws;                                // B*T*128 floats
    float* pB = pQ + (size_t)B * T * 128;                    // B*T floats

    k_lse_gather<<<B * T, 256, 0, stream>>>(logits, targets, tgtlen, pQ, pB);
    k_ctc_alpha<<<B / WPB, WPB * 64, 0, stream>>>(pQ, pB, targets, loglen,
                                                  tgtlen, out);
}